// Round 1
// baseline (2034.407 us; speedup 1.0000x reference)
//
#include <hip/hip_runtime.h>
#include <cfloat>

// Problem constants (B=16,S=4096,H=512,G=2,V=320,D=128)
#define M_TOTAL 65536
#define K_H     512
#define GD      256
#define NG      2
#define ND      128
#define NV      320

// d_out float offsets: quantized [16,4096,256], encodings [2,16,4096,320],
// distances [2,16,4096,320], perplexity scalar
#define Q_OFF     0
#define ENC_OFF   16777216
#define DIST_OFF  58720256
#define PERP_OFF  100663296

typedef float f4v __attribute__((ext_vector_type(4)));

// ---- c2[g,v] = ||codevector||^2, precomputed into workspace ----
__global__ void c2_kernel(const float* __restrict__ C, float* __restrict__ c2out) {
  int gv = blockIdx.x * 64 + threadIdx.x;   // grid 10 x 64 = 640
  const float4* p = (const float4*)(C + (size_t)gv * ND);
  float s = 0.f;
#pragma unroll 8
  for (int q = 0; q < 32; ++q) {
    float4 v = p[q];
    s += v.x * v.x + v.y * v.y + v.z * v.z + v.w * v.w;
  }
  c2out[gv] = s;
}

// ---- fused: project -> distances -> argmin -> one-hot/hist/gather ----
// 64-row tile per block, 256 threads.
// LDS = 32 KB h-tile + 7.3 KB phase-1 staging = ~40 KB -> 4 blocks/CU
// (16 waves/CU, 50% occupancy; 1024 blocks = exactly one resident round).
// Phase 2 reads codevectors straight from global (C = 320 KB, L2-resident),
// so phase 2 is barrier-free. Encodings are written in-kernel (no memset).
__global__ __launch_bounds__(256, 4) void quant_main(
    const float* __restrict__ X,     // [65536,512]
    const float* __restrict__ W,     // [512,256]
    const float* __restrict__ bias,  // [256]
    const float* __restrict__ C,     // [2,320,128]
    const float* __restrict__ c2,    // ws: [2,320]
    int* __restrict__ hist,          // ws: [2,320]
    float* __restrict__ out) {
  // hs: h-tile [64][128] XOR-swizzled (32 KB)
  // reg2: phase-1 staging As_T 8x68=544 + Ws 8x160=1280 (also idx share)
  __shared__ float hs[64 * 128];
  __shared__ float reg2[1824];

  const int t   = threadIdx.x;
  const int tx  = t & 15;       // lane%16 within wave
  const int ty  = t >> 4;       // 0..15
  const int row0 = blockIdx.x * 64;

  float* out_q    = out + Q_OFF;
  float* out_enc  = out + ENC_OFF;
  float* out_dist = out + DIST_OFF;

  for (int g = 0; g < NG; ++g) {
    // ================= phase 1: h_g tile = X[rows] @ W[:, g*128..] + b ======
    // K-step = 8 (halved vs 16 so staging fits 7.3 KB; same k summation order)
    float acc1[4][8];  // rows 4*ty+i, cols g*128 + 8*tx + j
#pragma unroll
    for (int i = 0; i < 4; ++i)
#pragma unroll
      for (int j = 0; j < 8; ++j) acc1[i][j] = 0.f;

    for (int kc = 0; kc < 64; ++kc) {
      __syncthreads();  // reg2 reuse barrier
      // As_T[k][r] at reg2[68*k + r], k=0..7, r=0..63
      {
        int r = t >> 2, kq = t & 3;
        float2 x2 = *(const float2*)(X + (size_t)(row0 + r) * K_H + kc * 8 + 2 * kq);
        reg2[68 * (2 * kq + 0) + r] = x2.x;
        reg2[68 * (2 * kq + 1) + r] = x2.y;
      }
      // Ws[k][c] at reg2[544 + 160*k + 20*(c>>4) + (c&15)], quad-padded
      {
        int k = t >> 5, c4 = t & 31;
        float4 w4 = *(const float4*)(W + (size_t)(kc * 8 + k) * GD + g * ND + 4 * c4);
        *(float4*)&reg2[544 + 160 * k + 20 * (c4 >> 2) + 4 * (c4 & 3)] = w4;
      }
      __syncthreads();
#pragma unroll
      for (int k = 0; k < 8; ++k) {
        float4 a = *(const float4*)&reg2[68 * k + 4 * ty];
        int wb = 544 + 160 * k + 20 * (tx >> 1) + 8 * (tx & 1);
        float4 w0 = *(const float4*)&reg2[wb];
        float4 w1 = *(const float4*)&reg2[wb + 4];
        float av[4] = {a.x, a.y, a.z, a.w};
        float wv[8] = {w0.x, w0.y, w0.z, w0.w, w1.x, w1.y, w1.z, w1.w};
#pragma unroll
        for (int i = 0; i < 4; ++i)
#pragma unroll
          for (int j = 0; j < 8; ++j) acc1[i][j] += av[i] * wv[j];
      }
    }
    // bias
#pragma unroll
    for (int j = 0; j < 8; ++j) {
      float bj = bias[g * ND + 8 * tx + j];
#pragma unroll
      for (int i = 0; i < 4; ++i) acc1[i][j] += bj;
    }
    // write h tile to LDS, XOR-swizzled: hs[r][d] at 128*r + 4*((d>>2)^(r&7)) + (d&3)
#pragma unroll
    for (int i = 0; i < 4; ++i) {
      int r = 4 * ty + i, sw = r & 7;
      float4 v0 = make_float4(acc1[i][0], acc1[i][1], acc1[i][2], acc1[i][3]);
      float4 v1 = make_float4(acc1[i][4], acc1[i][5], acc1[i][6], acc1[i][7]);
      *(float4*)&hs[128 * r + 4 * ((2 * tx) ^ sw)]     = v0;
      *(float4*)&hs[128 * r + 4 * ((2 * tx + 1) ^ sw)] = v1;
    }
    __syncthreads();

    // h2 per row, kept in registers (shuffle-reduced across the 16 tx lanes)
    float h2r[4];
#pragma unroll
    for (int i = 0; i < 4; ++i) {
      int r = 4 * ty + i, sw = r & 7;
      float s = 0.f;
#pragma unroll
      for (int qq = 0; qq < 2; ++qq) {
        int q = tx + 16 * qq;
        float4 v = *(const float4*)&hs[128 * r + 4 * (q ^ sw)];
        s += v.x * v.x + v.y * v.y + v.z * v.z + v.w * v.w;
      }
#pragma unroll
      for (int off = 1; off < 16; off <<= 1) s += __shfl_xor(s, off);
      h2r[i] = s;
    }

    // ====== phase 2: distances + argmin, C from global (L2), barrier-free ===
    float runval[4]; int runidx[4];
#pragma unroll
    for (int i = 0; i < 4; ++i) { runval[i] = FLT_MAX; runidx[i] = 0; }

    for (int vc = 0; vc < 4; ++vc) {           // 4 register chunks of 80 v
      int vb = 80 * vc;
      float acc[4][5];
#pragma unroll
      for (int i = 0; i < 4; ++i)
#pragma unroll
        for (int j = 0; j < 5; ++j) acc[i][j] = 0.f;
      const float* Cg = C + (size_t)(g * NV + vb + tx) * ND;  // + j*2048 + 4q
#pragma unroll 4
      for (int q = 0; q < 32; ++q) {
        float4 a[4];
#pragma unroll
        for (int i = 0; i < 4; ++i) {
          int r = 4 * ty + i;
          a[i] = *(const float4*)&hs[128 * r + 4 * (q ^ (r & 7))];
        }
#pragma unroll
        for (int j = 0; j < 5; ++j) {
          float4 b = *(const float4*)(Cg + (size_t)(2048 * j) + 4 * q);
#pragma unroll
          for (int i = 0; i < 4; ++i)
            acc[i][j] += a[i].x * b.x + a[i].y * b.y +
                         a[i].z * b.z + a[i].w * b.w;
        }
      }
      float c2v[5];
#pragma unroll
      for (int j = 0; j < 5; ++j) c2v[j] = c2[g * NV + vb + tx + 16 * j];
#pragma unroll
      for (int i = 0; i < 4; ++i) {
        int rg = row0 + 4 * ty + i;
        size_t dbase = (size_t)(g * M_TOTAL + rg) * NV + vb;
#pragma unroll
        for (int j = 0; j < 5; ++j) {   // j ascending -> v ascending (argmin-first)
          float d = h2r[i] - 2.f * acc[i][j] + c2v[j];
          __builtin_nontemporal_store(d, out_dist + dbase + tx + 16 * j);
          int vidx = vb + tx + 16 * j;
          if (d < runval[i]) { runval[i] = d; runidx[i] = vidx; }
        }
      }
    }

    // argmin reduce across the 16 tx lanes (tie -> lower index, like jnp.argmin)
    int fidx[4];
#pragma unroll
    for (int i = 0; i < 4; ++i) {
      float v = runval[i]; int idx = runidx[i];
#pragma unroll
      for (int off = 1; off < 16; off <<= 1) {
        float ov = __shfl_xor(v, off);
        int oi = __shfl_xor(idx, off);
        if (ov < v || (ov == v && oi < idx)) { v = ov; idx = oi; }
      }
      fidx[i] = idx;
      if (tx == 0) atomicAdd(&hist[g * NV + idx], 1);
    }

    // one-hot encodings written directly (replaces the 168 MB memset):
    // fidx[i] is uniform across the 16 tx lanes; each lane covers 5 quads.
#pragma unroll
    for (int i = 0; i < 4; ++i) {
      int rg = row0 + 4 * ty + i;
      float* rowp = out_enc + (size_t)(g * M_TOTAL + rg) * NV;
      int fi = fidx[i];
#pragma unroll
      for (int jj = 0; jj < 5; ++jj) {
        int q = tx + 16 * jj;     // 16 lanes -> 256 B contiguous per (i,jj)
        f4v e;
        e.x = (fi == 4 * q + 0) ? 1.f : 0.f;
        e.y = (fi == 4 * q + 1) ? 1.f : 0.f;
        e.z = (fi == 4 * q + 2) ? 1.f : 0.f;
        e.w = (fi == 4 * q + 3) ? 1.f : 0.f;
        __builtin_nontemporal_store(e, (f4v*)(rowp + 4 * q));
      }
    }

    // share idx via reg2 (phase-1 staging long dead; all waves past hs barrier)
    if (tx == 0) {
#pragma unroll
      for (int i = 0; i < 4; ++i) ((int*)reg2)[4 * ty + i] = fidx[i];
    }
    __syncthreads();
    // cooperative quantized-feature gather (float4, coalesced)
#pragma unroll
    for (int it = 0; it < 8; ++it) {
      int flat = t + 256 * it;     // 0..2047: 64 rows x 32 quads
      int r = flat >> 5, q = flat & 31;
      int idx = ((int*)reg2)[r];
      float4 cv = *(const float4*)(C + (size_t)((g * NV + idx) * ND) + 4 * q);
      *(float4*)(out_q + (size_t)(row0 + r) * GD + g * ND + 4 * q) = cv;
    }
  }
}

// ---- perplexity from histogram ----
__global__ void perp_kernel(const int* __restrict__ hist, float* __restrict__ outp) {
  int t = threadIdx.x;  // 64 threads = 1 wave
  float s0 = 0.f, s1 = 0.f;
  for (int v = t; v < NV; v += 64) {
    float p0 = fminf(fmaxf((float)hist[v] * (1.0f / 65536.f), 1e-10f), 1.0f);
    float p1 = fminf(fmaxf((float)hist[NV + v] * (1.0f / 65536.f), 1e-10f), 1.0f);
    s0 += p0 * logf(p0 + 1e-10f);
    s1 += p1 * logf(p1 + 1e-10f);
  }
#pragma unroll
  for (int off = 1; off < 64; off <<= 1) {
    s0 += __shfl_xor(s0, off);
    s1 += __shfl_xor(s1, off);
  }
  if (t == 0) outp[0] = 0.5f * (expf(-s0) + expf(-s1));
}

extern "C" void kernel_launch(void* const* d_in, const int* in_sizes, int n_in,
                              void* d_out, int out_size, void* d_ws, size_t ws_size,
                              hipStream_t stream) {
  const float* X    = (const float*)d_in[0];
  const float* W    = (const float*)d_in[1];
  const float* bias = (const float*)d_in[2];
  const float* C    = (const float*)d_in[3];
  float* out = (float*)d_out;

  int*   hist = (int*)d_ws;                 // [2,320] ints
  float* c2   = (float*)d_ws + 1024;        // [2,320] floats

  // only the histogram needs zeroing now (encodings are fully written in-kernel)
  hipMemsetAsync(d_ws, 0, 4096, stream);

  c2_kernel<<<10, 64, 0, stream>>>(C, c2);
  quant_main<<<1024, 256, 0, stream>>>(X, W, bias, C, c2, hist, out);
  perp_kernel<<<1, 64, 0, stream>>>(hist, out + PERP_OFF);
}

// Round 2
// 2019.554 us; speedup vs baseline: 1.0074x; 1.0074x over previous
//
#include <hip/hip_runtime.h>
#include <cfloat>

// Problem constants (B=16,S=4096,H=512,G=2,V=320,D=128)
#define M_TOTAL 65536
#define K_H     512
#define GD      256
#define NG      2
#define ND      128
#define NV      320

// d_out float offsets: quantized [16,4096,256], encodings [2,16,4096,320],
// distances [2,16,4096,320], perplexity scalar
#define Q_OFF     0
#define ENC_OFF   16777216
#define DIST_OFF  58720256
#define PERP_OFF  100663296

// ---- c2[g,v] = ||codevector||^2, precomputed into workspace ----
__global__ void c2_kernel(const float* __restrict__ C, float* __restrict__ c2out) {
  int gv = blockIdx.x * 64 + threadIdx.x;   // grid 10 x 64 = 640
  const float4* p = (const float4*)(C + (size_t)gv * ND);
  float s = 0.f;
#pragma unroll 8
  for (int q = 0; q < 32; ++q) {
    float4 v = p[q];
    s += v.x * v.x + v.y * v.y + v.z * v.z + v.w * v.w;
  }
  c2out[gv] = s;
}

// ---- fused: project -> distances -> argmin -> one-hot/hist/gather ----
// 64-row tile per block, 256 threads.
// LDS = 32 KB h-tile + 7.3 KB phase-1 staging = ~40 KB -> 4 blocks/CU
// (16 waves/CU, 50% occupancy; 1024 blocks = exactly one resident round).
// Phase 2 reads codevectors straight from global (C = 320 KB, L2-resident;
// L1 dedups the 16x ty-reuse), so phase 2 is barrier-free.
// Encodings written in-kernel (no 168 MB memset). ALL stores are plain
// (round-1 lesson: nontemporal stores caused 11x write amplification +
// L2 sweep that evicted C -> 4.1 GB HBM traffic, 2.2x regression).
__global__ __launch_bounds__(256, 4) void quant_main(
    const float* __restrict__ X,     // [65536,512]
    const float* __restrict__ W,     // [512,256]
    const float* __restrict__ bias,  // [256]
    const float* __restrict__ C,     // [2,320,128]
    const float* __restrict__ c2,    // ws: [2,320]
    int* __restrict__ hist,          // ws: [2,320]
    float* __restrict__ out) {
  // hs: h-tile [64][128] XOR-swizzled (32 KB)
  // reg2: phase-1 staging As_T 8x68=544 + Ws 8x160=1280 (also idx share)
  __shared__ float hs[64 * 128];
  __shared__ float reg2[1824];

  const int t   = threadIdx.x;
  const int tx  = t & 15;       // lane%16 within wave
  const int ty  = t >> 4;       // 0..15
  const int row0 = blockIdx.x * 64;

  float* out_q    = out + Q_OFF;
  float* out_enc  = out + ENC_OFF;
  float* out_dist = out + DIST_OFF;

  for (int g = 0; g < NG; ++g) {
    // ================= phase 1: h_g tile = X[rows] @ W[:, g*128..] + b ======
    // K-step = 8 (staging fits 7.3 KB; same k summation order as reference tile)
    float acc1[4][8];  // rows 4*ty+i, cols g*128 + 8*tx + j
#pragma unroll
    for (int i = 0; i < 4; ++i)
#pragma unroll
      for (int j = 0; j < 8; ++j) acc1[i][j] = 0.f;

    for (int kc = 0; kc < 64; ++kc) {
      __syncthreads();  // reg2 reuse barrier
      // As_T[k][r] at reg2[68*k + r], k=0..7, r=0..63
      {
        int r = t >> 2, kq = t & 3;
        float2 x2 = *(const float2*)(X + (size_t)(row0 + r) * K_H + kc * 8 + 2 * kq);
        reg2[68 * (2 * kq + 0) + r] = x2.x;
        reg2[68 * (2 * kq + 1) + r] = x2.y;
      }
      // Ws[k][c] at reg2[544 + 160*k + 20*(c>>4) + (c&15)], quad-padded
      {
        int k = t >> 5, c4 = t & 31;
        float4 w4 = *(const float4*)(W + (size_t)(kc * 8 + k) * GD + g * ND + 4 * c4);
        *(float4*)&reg2[544 + 160 * k + 20 * (c4 >> 2) + 4 * (c4 & 3)] = w4;
      }
      __syncthreads();
#pragma unroll
      for (int k = 0; k < 8; ++k) {
        float4 a = *(const float4*)&reg2[68 * k + 4 * ty];
        int wb = 544 + 160 * k + 20 * (tx >> 1) + 8 * (tx & 1);
        float4 w0 = *(const float4*)&reg2[wb];
        float4 w1 = *(const float4*)&reg2[wb + 4];
        float av[4] = {a.x, a.y, a.z, a.w};
        float wv[8] = {w0.x, w0.y, w0.z, w0.w, w1.x, w1.y, w1.z, w1.w};
#pragma unroll
        for (int i = 0; i < 4; ++i)
#pragma unroll
          for (int j = 0; j < 8; ++j) acc1[i][j] += av[i] * wv[j];
      }
    }
    // bias
#pragma unroll
    for (int j = 0; j < 8; ++j) {
      float bj = bias[g * ND + 8 * tx + j];
#pragma unroll
      for (int i = 0; i < 4; ++i) acc1[i][j] += bj;
    }
    // write h tile to LDS, XOR-swizzled: hs[r][d] at 128*r + 4*((d>>2)^(r&7)) + (d&3)
#pragma unroll
    for (int i = 0; i < 4; ++i) {
      int r = 4 * ty + i, sw = r & 7;
      float4 v0 = make_float4(acc1[i][0], acc1[i][1], acc1[i][2], acc1[i][3]);
      float4 v1 = make_float4(acc1[i][4], acc1[i][5], acc1[i][6], acc1[i][7]);
      *(float4*)&hs[128 * r + 4 * ((2 * tx) ^ sw)]     = v0;
      *(float4*)&hs[128 * r + 4 * ((2 * tx + 1) ^ sw)] = v1;
    }
    __syncthreads();

    // h2 per row, kept in registers (shuffle-reduced across the 16 tx lanes)
    float h2r[4];
#pragma unroll
    for (int i = 0; i < 4; ++i) {
      int r = 4 * ty + i, sw = r & 7;
      float s = 0.f;
#pragma unroll
      for (int qq = 0; qq < 2; ++qq) {
        int q = tx + 16 * qq;
        float4 v = *(const float4*)&hs[128 * r + 4 * (q ^ sw)];
        s += v.x * v.x + v.y * v.y + v.z * v.z + v.w * v.w;
      }
#pragma unroll
      for (int off = 1; off < 16; off <<= 1) s += __shfl_xor(s, off);
      h2r[i] = s;
    }

    // ====== phase 2: distances + argmin, C from global (L2), barrier-free ===
    float runval[4]; int runidx[4];
#pragma unroll
    for (int i = 0; i < 4; ++i) { runval[i] = FLT_MAX; runidx[i] = 0; }

    for (int vc = 0; vc < 4; ++vc) {           // 4 register chunks of 80 v
      int vb = 80 * vc;
      float acc[4][5];
#pragma unroll
      for (int i = 0; i < 4; ++i)
#pragma unroll
        for (int j = 0; j < 5; ++j) acc[i][j] = 0.f;
      const float* Cg = C + (size_t)(g * NV + vb + tx) * ND;  // + j*2048 + 4q
#pragma unroll 4
      for (int q = 0; q < 32; ++q) {
        float4 a[4];
#pragma unroll
        for (int i = 0; i < 4; ++i) {
          int r = 4 * ty + i;
          a[i] = *(const float4*)&hs[128 * r + 4 * (q ^ (r & 7))];
        }
#pragma unroll
        for (int j = 0; j < 5; ++j) {
          float4 b = *(const float4*)(Cg + (size_t)(2048 * j) + 4 * q);
#pragma unroll
          for (int i = 0; i < 4; ++i)
            acc[i][j] += a[i].x * b.x + a[i].y * b.y +
                         a[i].z * b.z + a[i].w * b.w;
        }
      }
      float c2v[5];
#pragma unroll
      for (int j = 0; j < 5; ++j) c2v[j] = c2[g * NV + vb + tx + 16 * j];
#pragma unroll
      for (int i = 0; i < 4; ++i) {
        int rg = row0 + 4 * ty + i;
        size_t dbase = (size_t)(g * M_TOTAL + rg) * NV + vb;
#pragma unroll
        for (int j = 0; j < 5; ++j) {   // j ascending -> v ascending (argmin-first)
          float d = h2r[i] - 2.f * acc[i][j] + c2v[j];
          out_dist[dbase + tx + 16 * j] = d;
          int vidx = vb + tx + 16 * j;
          if (d < runval[i]) { runval[i] = d; runidx[i] = vidx; }
        }
      }
    }

    // argmin reduce across the 16 tx lanes (tie -> lower index, like jnp.argmin)
    int fidx[4];
#pragma unroll
    for (int i = 0; i < 4; ++i) {
      float v = runval[i]; int idx = runidx[i];
#pragma unroll
      for (int off = 1; off < 16; off <<= 1) {
        float ov = __shfl_xor(v, off);
        int oi = __shfl_xor(idx, off);
        if (ov < v || (ov == v && oi < idx)) { v = ov; idx = oi; }
      }
      fidx[i] = idx;
      if (tx == 0) atomicAdd(&hist[g * NV + idx], 1);
    }

    // one-hot encodings written directly (replaces the 168 MB memset):
    // fidx[i] is uniform across the 16 tx lanes; each lane covers 5 quads.
#pragma unroll
    for (int i = 0; i < 4; ++i) {
      int rg = row0 + 4 * ty + i;
      float* rowp = out_enc + (size_t)(g * M_TOTAL + rg) * NV;
      int fi = fidx[i];
#pragma unroll
      for (int jj = 0; jj < 5; ++jj) {
        int q = tx + 16 * jj;     // 16 lanes -> 256 B contiguous per (i,jj)
        float4 e;
        e.x = (fi == 4 * q + 0) ? 1.f : 0.f;
        e.y = (fi == 4 * q + 1) ? 1.f : 0.f;
        e.z = (fi == 4 * q + 2) ? 1.f : 0.f;
        e.w = (fi == 4 * q + 3) ? 1.f : 0.f;
        *(float4*)(rowp + 4 * q) = e;
      }
    }

    // share idx via reg2 (phase-1 staging long dead; all waves past hs barrier)
    if (tx == 0) {
#pragma unroll
      for (int i = 0; i < 4; ++i) ((int*)reg2)[4 * ty + i] = fidx[i];
    }
    __syncthreads();
    // cooperative quantized-feature gather (float4, coalesced)
#pragma unroll
    for (int it = 0; it < 8; ++it) {
      int flat = t + 256 * it;     // 0..2047: 64 rows x 32 quads
      int r = flat >> 5, q = flat & 31;
      int idx = ((int*)reg2)[r];
      float4 cv = *(const float4*)(C + (size_t)((g * NV + idx) * ND) + 4 * q);
      *(float4*)(out_q + (size_t)(row0 + r) * GD + g * ND + 4 * q) = cv;
    }
  }
}

// ---- perplexity from histogram ----
__global__ void perp_kernel(const int* __restrict__ hist, float* __restrict__ outp) {
  int t = threadIdx.x;  // 64 threads = 1 wave
  float s0 = 0.f, s1 = 0.f;
  for (int v = t; v < NV; v += 64) {
    float p0 = fminf(fmaxf((float)hist[v] * (1.0f / 65536.f), 1e-10f), 1.0f);
    float p1 = fminf(fmaxf((float)hist[NV + v] * (1.0f / 65536.f), 1e-10f), 1.0f);
    s0 += p0 * logf(p0 + 1e-10f);
    s1 += p1 * logf(p1 + 1e-10f);
  }
#pragma unroll
  for (int off = 1; off < 64; off <<= 1) {
    s0 += __shfl_xor(s0, off);
    s1 += __shfl_xor(s1, off);
  }
  if (t == 0) outp[0] = 0.5f * (expf(-s0) + expf(-s1));
}

extern "C" void kernel_launch(void* const* d_in, const int* in_sizes, int n_in,
                              void* d_out, int out_size, void* d_ws, size_t ws_size,
                              hipStream_t stream) {
  const float* X    = (const float*)d_in[0];
  const float* W    = (const float*)d_in[1];
  const float* bias = (const float*)d_in[2];
  const float* C    = (const float*)d_in[3];
  float* out = (float*)d_out;

  int*   hist = (int*)d_ws;                 // [2,320] ints
  float* c2   = (float*)d_ws + 1024;        // [2,320] floats

  // only the histogram needs zeroing (encodings are fully written in-kernel)
  hipMemsetAsync(d_ws, 0, 4096, stream);

  c2_kernel<<<10, 64, 0, stream>>>(C, c2);
  quant_main<<<1024, 256, 0, stream>>>(X, W, bias, C, c2, hist, out);
  perp_kernel<<<1, 64, 0, stream>>>(hist, out + PERP_OFF);
}